// Round 13
// baseline (121.441 us; speedup 1.0000x reference)
//
#include <hip/hip_runtime.h>
#include <hip/hip_bf16.h>
#include <cstdint>
#include <cstddef>

#define BATCH 8
#define CINC  64
#define HH    128
#define WWW   128
#define COUTC 128
#define KKC   9
#define KDIM  576   // KK*CIN, k = kk*64 + c
#define HWC   (HH*WWW)      // 16384
#define NPX   (BATCH*HWC)   // 131072

#define WIN_W   64                    // window width = block width (no x halo)
#define WIN_SZ  (6*WIN_W*128)         // 49152 B
#define AT_BASE WIN_SZ
#define AT_SZ   (128*128)             // 16384 B (128 px x 128 B)
#define LDS_SZ  (WIN_SZ + 2*AT_SZ)    // 81920 B -> 2 blocks/CU

typedef float f32x4 __attribute__((ext_vector_type(4)));
typedef short bf16x8 __attribute__((ext_vector_type(8)));

static __device__ __forceinline__ unsigned short f2bf(float f){
    unsigned u = __builtin_bit_cast(unsigned, f);
    u += 0x7fffu + ((u >> 16) & 1u);
    return (unsigned short)(u >> 16);
}
static __device__ __forceinline__ float bf_lo(unsigned u){
    return __builtin_bit_cast(float, u << 16);
}
static __device__ __forceinline__ float bf_hi(unsigned u){
    return __builtin_bit_cast(float, u & 0xffff0000u);
}
static __device__ __forceinline__ unsigned cvtpk(float lo, float hi){
    unsigned r;
    asm("v_cvt_pk_bf16_f32 %0, %1, %2" : "=v"(r) : "v"(lo), "v"(hi));
    return r;
}

// ---------------- K0: pack weights to bf16 ---------------------------------
__global__ __launch_bounds__(256) void prep_weights(
        const float* __restrict__ off_w, const float* __restrict__ mod_w,
        const float* __restrict__ reg_w, const float* __restrict__ pre_w,
        unsigned short* __restrict__ Wb, unsigned short* __restrict__ Wc,
        unsigned short* __restrict__ Wp)
{
    int idx = blockIdx.x * 256 + threadIdx.x;
    if (idx < COUTC * KDIM) {
        int o = idx / KDIM, k = idx % KDIM;
        int kk = k >> 6, c = k & 63;
        Wb[idx] = f2bf(reg_w[(o * CINC + c) * KKC + kk]);
    }
    int idx2 = idx - COUTC * KDIM;
    if (idx2 >= 0 && idx2 < 32 * KDIM) {
        int o = idx2 / KDIM, k = idx2 % KDIM;
        int kk = k >> 6, c = k & 63;
        float v = 0.f;
        if (o < 18)      v = off_w[(o * CINC + c) * KKC + kk];
        else if (o < 27) v = mod_w[((o - 18) * CINC + c) * KKC + kk];
        Wc[idx2] = f2bf(v);
    }
    int idx3 = idx - (COUTC * KDIM + 32 * KDIM);
    if (idx3 >= 0 && idx3 < CINC * CINC)
        Wp[idx3] = f2bf(pre_w[idx3]);
}

// ---------------- K1: 1x1 conv via MFMA, NCHW f32 -> NHWC bf16 --------------
__global__ __launch_bounds__(256) void conv1x1(
        const float* __restrict__ x, const unsigned short* __restrict__ Wp,
        const float* __restrict__ pre_b, unsigned short* __restrict__ xp)
{
    __shared__ unsigned short slab[4][64 * 72];

    const int tid = threadIdx.x;
    const int lane = tid & 63;
    const int wv   = tid >> 6;
    const int l15  = lane & 15;
    const int l4   = lane >> 4;

    int bid = (int)blockIdx.x;
    int bswz = (bid & 7) * 64 + (bid >> 3);
    int pxb = bswz * 256 + wv * 64;
    int b = pxb >> 14, hw0 = pxb & 16383;
    const float* xb = x + (size_t)b * CINC * HWC + hw0;

    bf16x8 bw[4][2];
    #pragma unroll
    for (int fn = 0; fn < 4; ++fn)
        #pragma unroll
        for (int s = 0; s < 2; ++s)
            bw[fn][s] = *(const bf16x8*)(Wp + (size_t)(16*fn + l15) * 64 + 32*s + 8*l4);
    float pb[4];
    #pragma unroll
    for (int fn = 0; fn < 4; ++fn) pb[fn] = pre_b[16*fn + l15];

    f32x4 acc[4][4];
    #pragma unroll
    for (int su = 0; su < 4; ++su)
        #pragma unroll
        for (int fn = 0; fn < 4; ++fn) acc[su][fn] = (f32x4){0.f,0.f,0.f,0.f};

    #pragma unroll
    for (int su = 0; su < 4; ++su) {
        #pragma unroll
        for (int s = 0; s < 2; ++s) {
            float f[8];
            #pragma unroll
            for (int j = 0; j < 8; ++j)
                f[j] = xb[(size_t)(s*32 + 8*l4 + j) * HWC + su*16 + l15];
            unsigned pk[4];
            #pragma unroll
            for (int d = 0; d < 4; ++d) pk[d] = cvtpk(f[2*d], f[2*d+1]);
            bf16x8 A = __builtin_bit_cast(bf16x8, make_uint4(pk[0], pk[1], pk[2], pk[3]));
            #pragma unroll
            for (int fn = 0; fn < 4; ++fn)
                acc[su][fn] = __builtin_amdgcn_mfma_f32_16x16x32_bf16(A, bw[fn][s], acc[su][fn], 0,0,0);
        }
    }

    unsigned short* sl = slab[wv];
    #pragma unroll
    for (int su = 0; su < 4; ++su)
        #pragma unroll
        for (int fn = 0; fn < 4; ++fn)
            #pragma unroll
            for (int r = 0; r < 4; ++r)
                sl[(su*16 + 4*l4 + r) * 72 + 16*fn + l15] = f2bf(acc[su][fn][r] + pb[fn]);
    const uint4* srow = (const uint4*)(sl + lane * 72);
    uint4* drow = (uint4*)(xp + (size_t)(pxb + lane) * 64);
    #pragma unroll
    for (int q = 0; q < 8; ++q) drow[q] = srow[q];
}

// ---------------- K3: fused, 2 blocks/CU, r10 per-wave shape ----------------
// 1024 blocks x 256 thr (4 waves). Block = 2 rows x 64 px. LDS = 81,920 B
// exactly: window 6x64px x128B (swizzled, NO x-halo) + 2x16KB At dbuf
// => 2 co-resident blocks/CU: block B computes through block A's barriers,
// and barrier groups are 4 waves (was 8). Per-wave shape = r10 (lerp 2
// subtiles, GEMM M=128 x N=32, acc[8][2]) => live set >64 VGPR, so the
// allocator cannot squeeze to the slow 64-reg codegen (r11/r12 failure).
// Phase O reads its 3x3 halo directly from global (L2-hot, overlaps stage).
// Lerp x-escapes at interior block edges join the rare global fallback.
__global__ __launch_bounds__(256, 2) void gather_einsum(
        const unsigned short* __restrict__ xp,
        const unsigned short* __restrict__ Wb,
        const unsigned short* __restrict__ Wc,
        const float* __restrict__ off_b,
        const float* __restrict__ mod_b,
        float* __restrict__ out)
{
    __shared__ char smem[LDS_SZ];
    char* winc = smem;                       // [6][64] px, 128B, swizzled
    float* epi = (float*)smem;               // epilogue [128 co][130] f32

    const int tid  = (int)threadIdx.x;
    const int lane = tid & 63;
    const int wv   = tid >> 6;       // 0..3
    const int l15  = lane & 15;
    const int l4   = lane >> 4;

    int bid = (int)blockIdx.x;
    int bswz = (bid & 7) * 128 + (bid >> 3);  // image = bid&7 (1024%8==0)
    const int b   = bswz >> 7;
    const int rem = bswz & 127;
    const int h0  = (rem >> 1) << 1;          // row pair
    const int x0w = (rem & 1) << 6;           // x half

    const unsigned short* xpb = xp + (size_t)b * HWC * CINC;

    // ---- stage window rows h0-2..h0+3, x = x0w..x0w+63, swizzled ----
    #pragma unroll
    for (int i = 0; i < 12; ++i) {
        int c = i * 256 + tid;            // 0..3071 16B-chunks
        int r = c >> 9;                   // window row (512 chunks/row)
        int cr = c & 511;
        int wx = cr >> 3, g = cr & 7;
        int y = h0 - 2 + r;
        uint4 v = make_uint4(0u,0u,0u,0u);
        if ((unsigned)y < 128u)
            v = *(const uint4*)(xpb + ((size_t)y * 128 + x0w + wx) * 64 + g * 8);
        *(uint4*)(winc + (r*WIN_W + wx)*128 + ((g ^ (wx & 7)) << 4)) = v;
    }

    // ---- Phase O: offset/mask conv, inputs from GLOBAL (L2-hot) ----
    const int hrow = wv >> 1;            // row in pair
    const int xsl  = (wv & 1) * 32;      // x slice in row
    {
        f32x4 aco[2][2];                 // [j][fn]
        #pragma unroll
        for (int j = 0; j < 2; ++j)
            #pragma unroll
            for (int fn = 0; fn < 2; ++fn) aco[j][fn] = (f32x4){0.f,0.f,0.f,0.f};

        #pragma unroll
        for (int kk = 0; kk < 9; ++kk) {
            bf16x8 bc0[2], bc1[2];
            #pragma unroll
            for (int fn = 0; fn < 2; ++fn) {
                bc0[fn] = *(const bf16x8*)(Wc + (size_t)(16*fn + l15) * KDIM + kk*64 + 8*l4);
                bc1[fn] = *(const bf16x8*)(Wc + (size_t)(16*fn + l15) * KDIM + kk*64 + 32 + 8*l4);
            }
            int y = h0 + hrow + kk/3 - 1;
            bool yv = (unsigned)y < 128u;
            #pragma unroll
            for (int j = 0; j < 2; ++j) {
                int gx = x0w + xsl + j*16 + l15 + kk%3 - 1;
                bool val = yv && ((unsigned)gx < 128u);
                const uint4* src = (const uint4*)(xpb
                    + ((size_t)((y & 127) * 128 + (gx & 127))) * 64 + 8 * l4);
                uint4 z = make_uint4(0u,0u,0u,0u);
                uint4 a0 = val ? src[0] : z;
                uint4 a1 = val ? src[4] : z;
                bf16x8 A0 = __builtin_bit_cast(bf16x8, a0);
                bf16x8 A1 = __builtin_bit_cast(bf16x8, a1);
                #pragma unroll
                for (int fn = 0; fn < 2; ++fn) {
                    aco[j][fn] = __builtin_amdgcn_mfma_f32_16x16x32_bf16(A0, bc0[fn], aco[j][fn], 0,0,0);
                    aco[j][fn] = __builtin_amdgcn_mfma_f32_16x16x32_bf16(A1, bc1[fn], aco[j][fn], 0,0,0);
                }
            }
        }
        // D -> Dt[p][o] (pitch 29 f32) in At[0] area
        float* Dt = (float*)(smem + AT_BASE);
        #pragma unroll
        for (int j = 0; j < 2; ++j)
        #pragma unroll
        for (int fn = 0; fn < 2; ++fn) {
            int o = 16*fn + l15;
            #pragma unroll
            for (int r = 0; r < 4; ++r) {
                int pr = 4*l4 + r;
                int p  = hrow*64 + xsl + j*16 + pr;    // px within block
                float v = aco[j][fn][r];
                if (o < 18) {
                    v += off_b[o];
                    int k = o >> 1;
                    if ((o & 1) == 0) v += (float)(h0 + hrow - 1 + k/3);
                    else              v += (float)(x0w + xsl + j*16 + pr - 1 + (k % 3));
                } else if (o < 27) {
                    v = 2.f / (1.f + __expf(-(v + mod_b[o - 18])));
                }
                if (o < 27) Dt[p*29 + o] = v;
            }
        }
    }
    __syncthreads();

    // ---- Phase C: coords -> regs (wave's lerp px = wv*32 + j*16 + l15) ----
    float cy[2][9], cx[2][9], cm[2][9];
    {
        const float* Dt = (const float*)(smem + AT_BASE);
        #pragma unroll
        for (int j = 0; j < 2; ++j) {
            int p = wv*32 + j*16 + l15;
            #pragma unroll
            for (int kk = 0; kk < 9; ++kk) {
                cy[j][kk] = Dt[p*29 + 2*kk];
                cx[j][kk] = Dt[p*29 + 2*kk + 1];
                cm[j][kk] = Dt[p*29 + 18 + kk];
            }
        }
    }
    __syncthreads();   // coords read before lerp overwrites At[0]

    // ---- main pipelined loop ----
    f32x4 acc[8][2];
    #pragma unroll
    for (int m = 0; m < 8; ++m) { acc[m][0] = (f32x4){0.f,0.f,0.f,0.f};
                                  acc[m][1] = (f32x4){0.f,0.f,0.f,0.f}; }

    const unsigned short* wrow = Wb + (size_t)(32*wv + l15) * KDIM + 8*l4;
    const int sw  = l15 & 7;
    const int ao1 = (l4 ^ sw) << 4, ao2 = ((l4 + 4) ^ sw) << 4;

    #define LERP_TILE(kk_)  do {                                              \
        char* Ab = smem + AT_BASE + ((kk_) & 1) * AT_SZ;                      \
        _Pragma("unroll")                                                     \
        for (int j = 0; j < 2; ++j) {                                         \
            float Y = cy[j][kk_], X = cx[j][kk_], M = cm[j][kk_];             \
            float yf = floorf(Y), xf = floorf(X);                             \
            float wy = Y - yf, wx = X - xf;                                   \
            int y0 = (int)yf, x0i = (int)xf;                                  \
            int y1 = y0 + 1, x1 = x0i + 1;                                    \
            bool yv0 = (unsigned)y0 < 128u, yv1 = (unsigned)y1 < 128u;        \
            bool xv0 = (unsigned)x0i < 128u, xv1 = (unsigned)x1 < 128u;       \
            int wr0 = y0 - (h0 - 2), wr1 = wr0 + 1;                           \
            int wxi = x0i - x0w;                                              \
            bool inW0 = (unsigned)wxi < (unsigned)WIN_W;                      \
            bool inW1 = (unsigned)(wxi + 1) < (unsigned)WIN_W;                \
            int wc0 = wr0 < 0 ? 0 : (wr0 > 5 ? 5 : wr0);                      \
            int wc1 = wr1 < 0 ? 0 : (wr1 > 5 ? 5 : wr1);                      \
            int wx0 = wxi < 0 ? 0 : (wxi > WIN_W-1 ? WIN_W-1 : wxi);          \
            int wx1 = wxi+1 < 0 ? 0 : (wxi+1 > WIN_W-1 ? WIN_W-1 : wxi+1);    \
            int s0 = wx0 & 7, s1 = wx1 & 7;                                   \
            const char* r00 = winc + (wc0*WIN_W + wx0)*128;                   \
            const char* r01 = winc + (wc0*WIN_W + wx1)*128;                   \
            const char* r10 = winc + (wc1*WIN_W + wx0)*128;                   \
            const char* r11 = winc + (wc1*WIN_W + wx1)*128;                   \
            uint4 cb0 = *(const uint4*)(r00 + ((l4 ^ s0) << 4));              \
            uint4 cb1 = *(const uint4*)(r00 + (((l4+4) ^ s0) << 4));          \
            uint4 cb2 = *(const uint4*)(r01 + ((l4 ^ s1) << 4));              \
            uint4 cb3 = *(const uint4*)(r01 + (((l4+4) ^ s1) << 4));          \
            uint4 cb4 = *(const uint4*)(r10 + ((l4 ^ s0) << 4));              \
            uint4 cb5 = *(const uint4*)(r10 + (((l4+4) ^ s0) << 4));          \
            uint4 cb6 = *(const uint4*)(r11 + ((l4 ^ s1) << 4));              \
            uint4 cb7 = *(const uint4*)(r11 + (((l4+4) ^ s1) << 4));          \
            bool oob = (yv0 && (unsigned)wr0 > 5u) || (yv1 && (unsigned)wr1 > 5u) \
                    || (xv0 && !inW0) || (xv1 && !inW1);                      \
            if (__builtin_expect(oob, 0)) {                                   \
                int yc0 = y0 < 0 ? 0 : (y0 > 127 ? 127 : y0);                 \
                int yc1 = y1 < 0 ? 0 : (y1 > 127 ? 127 : y1);                 \
                int xc0 = x0i < 0 ? 0 : (x0i > 127 ? 127 : x0i);              \
                int xc1 = x1  < 0 ? 0 : (x1  > 127 ? 127 : x1);               \
                const unsigned short* p00 = xpb + (size_t)(yc0*128 + xc0)*64 + 8*l4; \
                const unsigned short* p01 = xpb + (size_t)(yc0*128 + xc1)*64 + 8*l4; \
                const unsigned short* p10 = xpb + (size_t)(yc1*128 + xc0)*64 + 8*l4; \
                const unsigned short* p11 = xpb + (size_t)(yc1*128 + xc1)*64 + 8*l4; \
                cb0 = *(const uint4*)(p00);  cb1 = *(const uint4*)(p00 + 32); \
                cb2 = *(const uint4*)(p01);  cb3 = *(const uint4*)(p01 + 32); \
                cb4 = *(const uint4*)(p10);  cb5 = *(const uint4*)(p10 + 32); \
                cb6 = *(const uint4*)(p11);  cb7 = *(const uint4*)(p11 + 32); \
            }                                                                 \
            float u00 = (1.f - wy) * (1.f - wx) * M * ((yv0 && xv0) ? 1.f : 0.f); \
            float u01 = (1.f - wy) * wx         * M * ((yv0 && xv1) ? 1.f : 0.f); \
            float u10 = wy * (1.f - wx)         * M * ((yv1 && xv0) ? 1.f : 0.f); \
            float u11 = wy * wx                 * M * ((yv1 && xv1) ? 1.f : 0.f); \
            unsigned pk0[4], pk1[4];                                          \
            _Pragma("unroll")                                                 \
            for (int d = 0; d < 4; ++d) {                                     \
                unsigned q00, q01, q10, q11;                                  \
                q00 = cb0[d]; q01 = cb2[d]; q10 = cb4[d]; q11 = cb6[d];       \
                {                                                             \
                    float slo = bf_lo(q00)*u00 + bf_lo(q01)*u01 + bf_lo(q10)*u10 + bf_lo(q11)*u11; \
                    float shi = bf_hi(q00)*u00 + bf_hi(q01)*u01 + bf_hi(q10)*u10 + bf_hi(q11)*u11; \
                    pk0[d] = cvtpk(slo, shi);                                 \
                }                                                             \
                q00 = cb1[d]; q01 = cb3[d]; q10 = cb5[d]; q11 = cb7[d];       \
                {                                                             \
                    float slo = bf_lo(q00)*u00 + bf_lo(q01)*u01 + bf_lo(q10)*u10 + bf_lo(q11)*u11; \
                    float shi = bf_hi(q00)*u00 + bf_hi(q01)*u01 + bf_hi(q10)*u10 + bf_hi(q11)*u11; \
                    pk1[d] = cvtpk(slo, shi);                                 \
                }                                                             \
            }                                                                 \
            int p = wv*32 + j*16 + l15;                                       \
            char* ab = Ab + p*128;                                            \
            *(uint4*)(ab + ao1) = make_uint4(pk0[0], pk0[1], pk0[2], pk0[3]); \
            *(uint4*)(ab + ao2) = make_uint4(pk1[0], pk1[1], pk1[2], pk1[3]); \
        }                                                                     \
    } while (0)

    #define GEMM_STEP(g_)  do {                                               \
        const char* Ab = smem + AT_BASE + ((g_) & 1) * AT_SZ;                 \
        bf16x8 Bf00 = *(const bf16x8*)(wrow + (g_)*64);                       \
        bf16x8 Bf01 = *(const bf16x8*)(wrow + (g_)*64 + 32);                  \
        bf16x8 Bf10 = *(const bf16x8*)(wrow + (size_t)16*KDIM + (g_)*64);     \
        bf16x8 Bf11 = *(const bf16x8*)(wrow + (size_t)16*KDIM + (g_)*64 + 32);\
        _Pragma("unroll")                                                     \
        for (int m = 0; m < 8; ++m) {                                         \
            const char* ar = Ab + (16*m + l15)*128;                           \
            bf16x8 A0 = *(const bf16x8*)(ar + ao1);                           \
            bf16x8 A1 = *(const bf16x8*)(ar + ao2);                           \
            acc[m][0] = __builtin_amdgcn_mfma_f32_16x16x32_bf16(A0, Bf00, acc[m][0], 0,0,0); \
            acc[m][0] = __builtin_amdgcn_mfma_f32_16x16x32_bf16(A1, Bf01, acc[m][0], 0,0,0); \
            acc[m][1] = __builtin_amdgcn_mfma_f32_16x16x32_bf16(A0, Bf10, acc[m][1], 0,0,0); \
            acc[m][1] = __builtin_amdgcn_mfma_f32_16x16x32_bf16(A1, Bf11, acc[m][1], 0,0,0); \
        }                                                                     \
    } while (0)

    // prologue
    LERP_TILE(0);
    __syncthreads();
    // steady state: lerp(kk) || GEMM(kk-1), one barrier per step
    #pragma unroll 1
    for (int kk = 1; kk < 9; ++kk) {
        LERP_TILE(kk);
        GEMM_STEP(kk - 1);
        __syncthreads();
    }
    // epilogue step
    GEMM_STEP(8);
    __syncthreads();

    #undef LERP_TILE
    #undef GEMM_STEP

    // ---- epilogue: acc -> LDS [co][px pitch 130] -> coalesced stores ----
    #pragma unroll
    for (int m = 0; m < 8; ++m)
        #pragma unroll
        for (int f = 0; f < 2; ++f)
            *(f32x4*)(epi + (size_t)(32*wv + 16*f + l15) * 130 + 16*m + 4*l4) = acc[m][f];
    __syncthreads();

    float* ob = out + (size_t)b * COUTC * HWC + h0 * 128 + x0w;
    #pragma unroll
    for (int it = 0; it < 16; ++it) {
        int idx = it * 256 + tid;         // 0..4095 f32x4
        int o = idx >> 5, q = idx & 31;   // co, px-quad
        int p = 4 * q;                    // px in block 0..124
        f32x4 v = *(const f32x4*)(epi + (size_t)o * 130 + p);
        *(f32x4*)(ob + (size_t)o * HWC + (p >> 6) * 128 + (p & 63)) = v;
    }
}

extern "C" void kernel_launch(void* const* d_in, const int* in_sizes, int n_in,
                              void* d_out, int out_size, void* d_ws, size_t ws_size,
                              hipStream_t stream)
{
    const float* x     = (const float*)d_in[0];
    const float* pre_w = (const float*)d_in[1];
    const float* pre_b = (const float*)d_in[2];
    const float* off_w = (const float*)d_in[3];
    const float* off_b = (const float*)d_in[4];
    const float* mod_w = (const float*)d_in[5];
    const float* mod_b = (const float*)d_in[6];
    const float* reg_w = (const float*)d_in[7];
    float* out = (float*)d_out;

    unsigned short* xp = (unsigned short*)d_ws;                              // 16,777,216 B
    unsigned short* Wb = (unsigned short*)((char*)d_ws + 16777216);          //    147,456 B
    unsigned short* Wc = (unsigned short*)((char*)d_ws + 16924672);          //     36,864 B
    unsigned short* Wp = (unsigned short*)((char*)d_ws + 16961536);          //      8,192 B

    prep_weights<<<dim3(376), dim3(256), 0, stream>>>(off_w, mod_w, reg_w, pre_w, Wb, Wc, Wp);
    conv1x1     <<<dim3(512), dim3(256), 0, stream>>>(x, Wp, pre_b, xp);
    gather_einsum<<<dim3(1024), dim3(256), 0, stream>>>(xp, Wb, Wc, off_b, mod_b, out);
}

// Round 14
// 83.894 us; speedup vs baseline: 1.4475x; 1.4475x over previous
//
#include <hip/hip_runtime.h>
#include <hip/hip_bf16.h>
#include <cstdint>
#include <cstddef>

#define BATCH 8
#define CINC  64
#define HH    128
#define WWW   128
#define COUTC 128
#define KKC   9
#define KDIM  576
#define HWC   (HH*WWW)      // 16384
#define NPX   (BATCH*HWC)   // 131072

#define DT_BASE 98304       // window = 6*128*128 B; Dt after it

typedef float f32x4 __attribute__((ext_vector_type(4)));
typedef short bf16x8 __attribute__((ext_vector_type(8)));

static __device__ __forceinline__ unsigned short f2bf(float f){
    unsigned u = __builtin_bit_cast(unsigned, f);
    u += 0x7fffu + ((u >> 16) & 1u);
    return (unsigned short)(u >> 16);
}
static __device__ __forceinline__ float bf_lo(unsigned u){
    return __builtin_bit_cast(float, u << 16);
}
static __device__ __forceinline__ float bf_hi(unsigned u){
    return __builtin_bit_cast(float, u & 0xffff0000u);
}
static __device__ __forceinline__ unsigned cvtpk(float lo, float hi){
    unsigned r;
    asm("v_cvt_pk_bf16_f32 %0, %1, %2" : "=v"(r) : "v"(lo), "v"(hi));
    return r;
}

// ---- K0: pack weights into per-wave-fragment coalesced layouts -------------
// Wb2: [kk][s][cog0..7] chunks of 1KB: lane L, elem j -> o=cog*16+(L&15),
//      c=32s+8*(L>>4)+j. Wc2: same with cog 0..1. Wp2: [s][fn0..3].
__global__ __launch_bounds__(256) void prep_weights(
        const float* __restrict__ off_w, const float* __restrict__ mod_w,
        const float* __restrict__ reg_w, const float* __restrict__ pre_w,
        unsigned short* __restrict__ Wb2, unsigned short* __restrict__ Wc2,
        unsigned short* __restrict__ Wp2)
{
    int idx = blockIdx.x * 256 + threadIdx.x;      // 0..96255
    if (idx < 73728) {
        int chunk = idx >> 9, within = idx & 511;
        int lane = within >> 3, j = within & 7;
        int kk = chunk >> 4, s = (chunk >> 3) & 1, cog = chunk & 7;
        int o = cog * 16 + (lane & 15);
        int c = 32*s + 8*(lane >> 4) + j;
        Wb2[idx] = f2bf(reg_w[(o * CINC + c) * KKC + kk]);
    }
    int idx2 = idx - 73728;
    if (idx2 >= 0 && idx2 < 18432) {
        int chunk = idx2 >> 9, within = idx2 & 511;
        int lane = within >> 3, j = within & 7;
        int kk = chunk >> 2, s = (chunk >> 1) & 1, cog = chunk & 1;
        int o = cog * 16 + (lane & 15);
        int c = 32*s + 8*(lane >> 4) + j;
        float v = 0.f;
        if (o < 18)      v = off_w[(o * CINC + c) * KKC + kk];
        else if (o < 27) v = mod_w[((o - 18) * CINC + c) * KKC + kk];
        Wc2[idx2] = f2bf(v);
    }
    int idx3 = idx - 92160;
    if (idx3 >= 0 && idx3 < 4096) {
        int chunk = idx3 >> 9, within = idx3 & 511;
        int lane = within >> 3, j = within & 7;
        int s = chunk >> 2, fn = chunk & 3;
        int o = fn * 16 + (lane & 15);
        int c = 32*s + 8*(lane >> 4) + j;
        Wp2[idx3] = f2bf(pre_w[o * CINC + c]);
    }
}

// ---- K1: 1x1 conv via MFMA, NCHW f32 -> NHWC bf16 --------------------------
__global__ __launch_bounds__(256) void conv1x1(
        const float* __restrict__ x, const unsigned short* __restrict__ Wp2,
        const float* __restrict__ pre_b, unsigned short* __restrict__ xp)
{
    __shared__ unsigned short slab[4][64 * 72];

    const int tid = threadIdx.x;
    const int lane = tid & 63;
    const int wv   = tid >> 6;
    const int l15  = lane & 15;
    const int l4   = lane >> 4;

    int bid = (int)blockIdx.x;
    int bswz = (bid & 7) * 64 + (bid >> 3);
    int pxb = bswz * 256 + wv * 64;
    int b = pxb >> 14, hw0 = pxb & 16383;
    const float* xb = x + (size_t)b * CINC * HWC + hw0;

    bf16x8 bw[4][2];
    #pragma unroll
    for (int fn = 0; fn < 4; ++fn)
        #pragma unroll
        for (int s = 0; s < 2; ++s)
            bw[fn][s] = *(const bf16x8*)(Wp2 + (size_t)(s*4 + fn) * 512 + lane * 8);
    float pb[4];
    #pragma unroll
    for (int fn = 0; fn < 4; ++fn) pb[fn] = pre_b[16*fn + l15];

    f32x4 acc[4][4];
    #pragma unroll
    for (int su = 0; su < 4; ++su)
        #pragma unroll
        for (int fn = 0; fn < 4; ++fn) acc[su][fn] = (f32x4){0.f,0.f,0.f,0.f};

    #pragma unroll
    for (int su = 0; su < 4; ++su) {
        #pragma unroll
        for (int s = 0; s < 2; ++s) {
            float f[8];
            #pragma unroll
            for (int j = 0; j < 8; ++j)
                f[j] = xb[(size_t)(s*32 + 8*l4 + j) * HWC + su*16 + l15];
            unsigned pk[4];
            #pragma unroll
            for (int d = 0; d < 4; ++d) pk[d] = cvtpk(f[2*d], f[2*d+1]);
            bf16x8 A = __builtin_bit_cast(bf16x8, make_uint4(pk[0], pk[1], pk[2], pk[3]));
            #pragma unroll
            for (int fn = 0; fn < 4; ++fn)
                acc[su][fn] = __builtin_amdgcn_mfma_f32_16x16x32_bf16(A, bw[fn][s], acc[su][fn], 0,0,0);
        }
    }

    unsigned short* sl = slab[wv];
    #pragma unroll
    for (int su = 0; su < 4; ++su)
        #pragma unroll
        for (int fn = 0; fn < 4; ++fn)
            #pragma unroll
            for (int r = 0; r < 4; ++r)
                sl[(su*16 + 4*l4 + r) * 72 + 16*fn + l15] = f2bf(acc[su][fn][r] + pb[fn]);
    const uint4* srow = (const uint4*)(sl + lane * 72);
    uint4* drow = (uint4*)(xp + (size_t)(pxb + lane) * 64);
    #pragma unroll
    for (int q = 0; q < 8; ++q) drow[q] = srow[q];
}

// ---- K3: fused, register-direct lerp->MFMA, barrier-free main loop ---------
// 512 blocks x 512 thr (8 waves, 2/SIMD, 1 block/CU). Block = 2 rows x 128px.
// LDS: window 6x128px x128B (swizzled, 98KB) + Dt coords (30KB); epi overlays.
// Wave owns 32 px x ALL 128 couts: lerp -> A-frags in REGISTERS -> MFMA
// directly (no At staging: -1.4MB LDS/block). B-frags = coalesced 1KB loads
// from Wb2 (L2-hot). Main loop has NO barriers (window read-only, coords in
// Dt are same-wave). Coords read from LDS per kk (no runtime-indexed arrays).
__global__ __launch_bounds__(512, 2) void gather_einsum(
        const unsigned short* __restrict__ xp,
        const unsigned short* __restrict__ Wb2,
        const unsigned short* __restrict__ Wc2,
        const float* __restrict__ off_b,
        const float* __restrict__ mod_b,
        float* __restrict__ out)
{
    __shared__ char smem[133120];
    char* winc = smem;                       // [6][128] px, 128B, swizzled
    float* epi = (float*)smem;               // epilogue [128 co][260] f32
    float* Dt  = (float*)(smem + DT_BASE);   // [256 px][29] f32 coords

    const int tid  = (int)threadIdx.x;
    const int lane = tid & 63;
    const int wv   = tid >> 6;       // 0..7
    const int l15  = lane & 15;
    const int l4   = lane >> 4;

    int bid = (int)blockIdx.x;
    int bswz = (bid & 7) * 64 + (bid >> 3);   // image = bid&7 (512%8==0)
    const int b  = bswz >> 6;
    const int h0 = (bswz & 63) * 2;

    const unsigned short* xpb = xp + (size_t)b * HWC * CINC;

    // ---- stage window rows h0-2..h0+3, swizzled ----
    #pragma unroll
    for (int i = 0; i < 12; ++i) {
        int c = i * 512 + tid;            // 0..6143
        int r = c >> 10;
        int c10 = c & 1023;
        int xph = c10 >> 3, g = c10 & 7;
        int y = h0 - 2 + r;
        uint4 v = make_uint4(0u,0u,0u,0u);
        if ((unsigned)y < 128u)
            v = *(const uint4*)(xpb + ((size_t)y * 128 + xph) * 64 + g * 8);
        *(uint4*)(winc + (r*128 + xph)*128 + ((g ^ (xph & 7)) << 4)) = v;
    }
    __syncthreads();

    // ---- Phase O: offset/mask conv from window (8 waves, 32 px each) ----
    const int hrow = wv >> 2;
    const int x0w  = (wv & 3) * 32;
    {
        f32x4 aco[2][2];
        #pragma unroll
        for (int j = 0; j < 2; ++j)
            #pragma unroll
            for (int fn = 0; fn < 2; ++fn) aco[j][fn] = (f32x4){0.f,0.f,0.f,0.f};

        #pragma unroll
        for (int kk = 0; kk < 9; ++kk) {
            bf16x8 bc0[2], bc1[2];
            #pragma unroll
            for (int fn = 0; fn < 2; ++fn) {
                bc0[fn] = *(const bf16x8*)(Wc2 + (size_t)(kk*4     + fn) * 512 + lane * 8);
                bc1[fn] = *(const bf16x8*)(Wc2 + (size_t)(kk*4 + 2 + fn) * 512 + lane * 8);
            }
            int wr_ = hrow + (kk / 3) + 1;
            #pragma unroll
            for (int j = 0; j < 2; ++j) {
                int xx = x0w + j*16 + l15 + (kk % 3) - 1;
                bool xv = (unsigned)xx < 128u;
                int xc = xx < 0 ? 0 : (xx > 127 ? 127 : xx);
                int sx = xc & 7;
                const char* rr = winc + (wr_*128 + xc)*128;
                uint4 a0 = *(const uint4*)(rr + ((l4 ^ sx) << 4));
                uint4 a1 = *(const uint4*)(rr + (((l4+4) ^ sx) << 4));
                if (!xv) { a0 = make_uint4(0,0,0,0); a1 = make_uint4(0,0,0,0); }
                bf16x8 A0 = __builtin_bit_cast(bf16x8, a0);
                bf16x8 A1 = __builtin_bit_cast(bf16x8, a1);
                #pragma unroll
                for (int fn = 0; fn < 2; ++fn) {
                    aco[j][fn] = __builtin_amdgcn_mfma_f32_16x16x32_bf16(A0, bc0[fn], aco[j][fn], 0,0,0);
                    aco[j][fn] = __builtin_amdgcn_mfma_f32_16x16x32_bf16(A1, bc1[fn], aco[j][fn], 0,0,0);
                }
            }
        }
        // D -> Dt[p][o] (pitch 29), p = wv*32 + j*16 + 4*l4 + r (same-wave use)
        #pragma unroll
        for (int j = 0; j < 2; ++j)
        #pragma unroll
        for (int fn = 0; fn < 2; ++fn) {
            int o = 16*fn + l15;
            #pragma unroll
            for (int r = 0; r < 4; ++r) {
                int pr = 4*l4 + r;
                int p  = wv*32 + j*16 + pr;
                float v = aco[j][fn][r];
                if (o < 18) {
                    v += off_b[o];
                    int k = o >> 1;
                    if ((o & 1) == 0) v += (float)(h0 + hrow - 1 + k/3);
                    else              v += (float)(x0w + j*16 + pr - 1 + (k % 3));
                } else if (o < 27) {
                    v = 2.f / (1.f + __expf(-(v + mod_b[o - 18])));
                }
                if (o < 27) Dt[p*29 + o] = v;
            }
        }
    }
    // no barrier: Dt entries are produced and consumed by the SAME wave

    // ---- main loop: per kk {coords from Dt; lerp -> A regs; 32 MFMA} -------
    f32x4 acc[2][8];
    #pragma unroll
    for (int j = 0; j < 2; ++j)
        #pragma unroll
        for (int fn = 0; fn < 8; ++fn) acc[j][fn] = (f32x4){0.f,0.f,0.f,0.f};

    #pragma unroll 1
    for (int kk = 0; kk < 9; ++kk) {
        // B half 0 (cog 0..3), both K-chunks — coalesced 1KB loads, L2-hot
        bf16x8 Bs0[4], Bs1[4];
        #pragma unroll
        for (int f = 0; f < 4; ++f) {
            Bs0[f] = *(const bf16x8*)(Wb2 + (size_t)(kk*16 +      f) * 512 + lane * 8);
            Bs1[f] = *(const bf16x8*)(Wb2 + (size_t)(kk*16 +  8 + f) * 512 + lane * 8);
        }

        bf16x8 A[2][2];
        #pragma unroll
        for (int j = 0; j < 2; ++j) {
            int p = wv*32 + j*16 + l15;
            float Y = Dt[p*29 + 2*kk];
            float X = Dt[p*29 + 2*kk + 1];
            float M = Dt[p*29 + 18 + kk];
            float yf = floorf(Y), xf = floorf(X);
            float wy = Y - yf, wx = X - xf;
            int y0 = (int)yf, x0i = (int)xf;
            int y1 = y0 + 1, x1 = x0i + 1;
            bool yv0 = (unsigned)y0 < 128u, yv1 = (unsigned)y1 < 128u;
            bool xv0 = (unsigned)x0i < 128u, xv1 = (unsigned)x1 < 128u;
            int xc0 = x0i < 0 ? 0 : (x0i > 127 ? 127 : x0i);
            int xc1 = x1  < 0 ? 0 : (x1  > 127 ? 127 : x1);
            int wr0 = y0 - (h0 - 2), wr1 = wr0 + 1;
            int wc0 = wr0 < 0 ? 0 : (wr0 > 5 ? 5 : wr0);
            int wc1 = wr1 < 0 ? 0 : (wr1 > 5 ? 5 : wr1);
            int s0 = xc0 & 7, s1 = xc1 & 7;

            const char* r00 = winc + (wc0*128 + xc0)*128;
            const char* r01 = winc + (wc0*128 + xc1)*128;
            const char* r10 = winc + (wc1*128 + xc0)*128;
            const char* r11 = winc + (wc1*128 + xc1)*128;
            uint4 cb0 = *(const uint4*)(r00 + ((l4 ^ s0) << 4));
            uint4 cb1 = *(const uint4*)(r00 + (((l4+4) ^ s0) << 4));
            uint4 cb2 = *(const uint4*)(r01 + ((l4 ^ s1) << 4));
            uint4 cb3 = *(const uint4*)(r01 + (((l4+4) ^ s1) << 4));
            uint4 cb4 = *(const uint4*)(r10 + ((l4 ^ s0) << 4));
            uint4 cb5 = *(const uint4*)(r10 + (((l4+4) ^ s0) << 4));
            uint4 cb6 = *(const uint4*)(r11 + ((l4 ^ s1) << 4));
            uint4 cb7 = *(const uint4*)(r11 + (((l4+4) ^ s1) << 4));

            bool oob = (yv0 && (unsigned)wr0 > 5u) || (yv1 && (unsigned)wr1 > 5u);
            if (__builtin_expect(oob, 0)) {
                int yc0 = y0 < 0 ? 0 : (y0 > 127 ? 127 : y0);
                int yc1 = y1 < 0 ? 0 : (y1 > 127 ? 127 : y1);
                const unsigned short* p00 = xpb + (size_t)(yc0*128 + xc0)*64 + 8*l4;
                const unsigned short* p01 = xpb + (size_t)(yc0*128 + xc1)*64 + 8*l4;
                const unsigned short* p10 = xpb + (size_t)(yc1*128 + xc0)*64 + 8*l4;
                const unsigned short* p11 = xpb + (size_t)(yc1*128 + xc1)*64 + 8*l4;
                cb0 = *(const uint4*)(p00);  cb1 = *(const uint4*)(p00 + 32);
                cb2 = *(const uint4*)(p01);  cb3 = *(const uint4*)(p01 + 32);
                cb4 = *(const uint4*)(p10);  cb5 = *(const uint4*)(p10 + 32);
                cb6 = *(const uint4*)(p11);  cb7 = *(const uint4*)(p11 + 32);
            }

            float u00 = (1.f - wy) * (1.f - wx) * M * ((yv0 && xv0) ? 1.f : 0.f);
            float u01 = (1.f - wy) * wx         * M * ((yv0 && xv1) ? 1.f : 0.f);
            float u10 = wy * (1.f - wx)         * M * ((yv1 && xv0) ? 1.f : 0.f);
            float u11 = wy * wx                 * M * ((yv1 && xv1) ? 1.f : 0.f);

            unsigned pk0[4], pk1[4];
            #pragma unroll
            for (int d = 0; d < 4; ++d) {
                unsigned q00, q01, q10, q11;
                q00 = cb0[d]; q01 = cb2[d]; q10 = cb4[d]; q11 = cb6[d];
                {
                    float slo = bf_lo(q00)*u00 + bf_lo(q01)*u01 + bf_lo(q10)*u10 + bf_lo(q11)*u11;
                    float shi = bf_hi(q00)*u00 + bf_hi(q01)*u01 + bf_hi(q10)*u10 + bf_hi(q11)*u11;
                    pk0[d] = cvtpk(slo, shi);
                }
                q00 = cb1[d]; q01 = cb3[d]; q10 = cb5[d]; q11 = cb7[d];
                {
                    float slo = bf_lo(q00)*u00 + bf_lo(q01)*u01 + bf_lo(q10)*u10 + bf_lo(q11)*u11;
                    float shi = bf_hi(q00)*u00 + bf_hi(q01)*u01 + bf_hi(q10)*u10 + bf_hi(q11)*u11;
                    pk1[d] = cvtpk(slo, shi);
                }
            }
            A[j][0] = __builtin_bit_cast(bf16x8, make_uint4(pk0[0], pk0[1], pk0[2], pk0[3]));
            A[j][1] = __builtin_bit_cast(bf16x8, make_uint4(pk1[0], pk1[1], pk1[2], pk1[3]));
        }

        // MFMA half 0 (couts 0..63)
        #pragma unroll
        for (int j = 0; j < 2; ++j)
            #pragma unroll
            for (int f = 0; f < 4; ++f) {
                acc[j][f] = __builtin_amdgcn_mfma_f32_16x16x32_bf16(A[j][0], Bs0[f], acc[j][f], 0,0,0);
                acc[j][f] = __builtin_amdgcn_mfma_f32_16x16x32_bf16(A[j][1], Bs1[f], acc[j][f], 0,0,0);
            }

        // B half 1 (cog 4..7) + MFMA
        #pragma unroll
        for (int f = 0; f < 4; ++f) {
            Bs0[f] = *(const bf16x8*)(Wb2 + (size_t)(kk*16 +  4 + f) * 512 + lane * 8);
            Bs1[f] = *(const bf16x8*)(Wb2 + (size_t)(kk*16 + 12 + f) * 512 + lane * 8);
        }
        #pragma unroll
        for (int j = 0; j < 2; ++j)
            #pragma unroll
            for (int f = 0; f < 4; ++f) {
                acc[j][4+f] = __builtin_amdgcn_mfma_f32_16x16x32_bf16(A[j][0], Bs0[f], acc[j][4+f], 0,0,0);
                acc[j][4+f] = __builtin_amdgcn_mfma_f32_16x16x32_bf16(A[j][1], Bs1[f], acc[j][4+f], 0,0,0);
            }
    }

    // ---- epilogue: acc -> LDS [co][px pitch 260] -> coalesced stores ----
    __syncthreads();   // all waves done reading window/Dt; safe to overlay epi
    #pragma unroll
    for (int j = 0; j < 2; ++j)
        #pragma unroll
        for (int fn = 0; fn < 8; ++fn)
            *(f32x4*)(epi + (size_t)(16*fn + l15) * 260 + 32*wv + 16*j + 4*l4) = acc[j][fn];
    __syncthreads();

    float* ob = out + (size_t)b * COUTC * HWC + h0 * 128;
    #pragma unroll
    for (int it = 0; it < 16; ++it) {
        int idx = it * 512 + tid;
        int o = idx >> 6, c = idx & 63;
        f32x4 v = *(const f32x4*)(epi + (size_t)o * 260 + 4*c);
        *(f32x4*)(ob + (size_t)o * HWC + 4*c) = v;
    }
}

extern "C" void kernel_launch(void* const* d_in, const int* in_sizes, int n_in,
                              void* d_out, int out_size, void* d_ws, size_t ws_size,
                              hipStream_t stream)
{
    const float* x     = (const float*)d_in[0];
    const float* pre_w = (const float*)d_in[1];
    const float* pre_b = (const float*)d_in[2];
    const float* off_w = (const float*)d_in[3];
    const float* off_b = (const float*)d_in[4];
    const float* mod_w = (const float*)d_in[5];
    const float* mod_b = (const float*)d_in[6];
    const float* reg_w = (const float*)d_in[7];
    float* out = (float*)d_out;

    unsigned short* xp  = (unsigned short*)d_ws;                             // 16,777,216 B
    unsigned short* Wb2 = (unsigned short*)((char*)d_ws + 16777216);         //    147,456 B
    unsigned short* Wc2 = (unsigned short*)((char*)d_ws + 16924672);         //     36,864 B
    unsigned short* Wp2 = (unsigned short*)((char*)d_ws + 16961536);         //      8,192 B

    prep_weights<<<dim3(376), dim3(256), 0, stream>>>(off_w, mod_w, reg_w, pre_w, Wb2, Wc2, Wp2);
    conv1x1     <<<dim3(512), dim3(256), 0, stream>>>(x, Wp2, pre_b, xp);
    gather_einsum<<<dim3(512), dim3(512), 0, stream>>>(xp, Wb2, Wc2, off_b, mod_b, out);
}